// Round 3
// baseline (113.563 us; speedup 1.0000x reference)
//
#include <hip/hip_runtime.h>
#include <math.h>

#define NPG  128
#define HID  128
#define KSEL 64
#define NT   512   // 8 waves = 4 row-tiles x 2 col-halves; 2 blocks/CU -> 4 waves/SIMD
#define HS   132   // H0' row stride in dwords: [128 hi us][128 lo us][pad]; 132%32==4
#define AS   17    // AdjN row stride in dwords (odd -> spread banks)
#define FS   516   // W1 frag-pair stride in dwords: [hi 256 dw][lo 256 dw][pad 4]

typedef __attribute__((ext_vector_type(8))) __bf16 bfrag;   // 8 bf16 = 4 VGPRs
typedef __attribute__((ext_vector_type(4))) float f4;

static __device__ __forceinline__ unsigned short bf2us(__bf16 b) {
    union { unsigned short s; __bf16 b; } x; x.b = b; return x.s;
}

// Single fused kernel, one block per graph, 8 waves.
// Wave (rt4 = wv&3, ch = wv>>2): owns rows rt4*32..+31, feature cols ch*64..+63.
// Column-split keeps total LDS B-frag traffic identical to the 4-wave version
// (each frag-pair read by exactly 2 waves' worth of rows, as before) while
// doubling waves/SIMD 2->4 for latency hiding.
// LDS phase plan for HpT region (67,584 B):
//   phase A: W1 bf16 B-frags, hi-block + lo-block per frag-pair (ds_read_b128 = bfrag)
//   phase B: H0' (rs-scaled x@W1) feature-major, per row [hi x128][lo x128]
//   phase C: Wlin staged linear [k][n] (64 KB) for the output GEMM
__global__ __launch_bounds__(NT, 4) void sagpool_fused(
    const float* __restrict__ x,
    const int*   __restrict__ esrc,
    const int*   __restrict__ edst,
    const float* __restrict__ W1,
    const float* __restrict__ b1,
    const float* __restrict__ Ws,
    const float* __restrict__ bsp,
    const float* __restrict__ Wlin,
    const float* __restrict__ blin,
    float* __restrict__ out,
    int epg)
{
    __shared__ __align__(16) unsigned HpT[HID * HS];   // 67,584 B (see phase plan)
    __shared__ __align__(16) unsigned AdjN[NPG * AS];  // nibble counts; reused as out-partials
    __shared__ __align__(16) float rsl[NPG];
    __shared__ __align__(16) float spl[2 * NPG];       // per-column-half partial spl
    __shared__ __align__(16) float scl[NPG];           // scores; reused as pooled
    __shared__ __align__(16) float wgt[NPG];
    __shared__ __align__(16) float pp[4 * HID];

    const int g = blockIdx.x, t = threadIdx.x;
    const int node0 = g * NPG;
    const long e0 = (long)g * epg;
    const int lane = t & 63, wv = t >> 6;         // wv in [0,8)
    const int rt4 = wv & 3, ch = wv >> 2;
    const int n16 = lane & 15, quad = lane >> 4;
    const int m0 = rt4 * 32;                      // this wave's 32-row tile

    // ---- early independent global loads: edges, x rows ----
    int es[4], ed[4];
#pragma unroll
    for (int i = 0; i < 4; ++i) {
        int e = i * NT + t;
        es[i] = esrc[e0 + e] - node0;
        ed[i] = edst[e0 + e] - node0;
    }
    bfrag ah[8], al[8];   // A-frags for 2 row-tiles x 4 k-slices (rows m0..m0+31)
    {
        const float* xw = x + (long)(node0 + m0) * HID;
#pragma unroll
        for (int rt = 0; rt < 2; ++rt)
#pragma unroll
            for (int ks = 0; ks < 4; ++ks) {
                const float* xr = xw + (rt * 16 + n16) * HID + ks * 32 + quad * 8;
                float4 a = *reinterpret_cast<const float4*>(xr);
                float4 b = *reinterpret_cast<const float4*>(xr + 4);
                float vv[8] = {a.x, a.y, a.z, a.w, b.x, b.y, b.z, b.w};
                const int r = rt * 4 + ks;
#pragma unroll
                for (int j = 0; j < 8; ++j) {
                    __bf16 hb = (__bf16)vv[j];
                    ah[r][j] = hb;
                    al[r][j] = (__bf16)(vv[j] - (float)hb);
                }
            }
    }

    // ---- zero AdjN ----
    for (int i = t; i < NPG * AS; i += NT) AdjN[i] = 0u;
    __syncthreads();

    // ---- phase: stage W1 -> LDS frag-pairs (hi-block|lo-block) + edge atomics ----
    // Fragment (ks,ct): lane holds B[k=ks*32+quad*8+j][n=ct*16+n16] as 8 bf16 (16B);
    // hi at pairbase + lane*16B, lo at pairbase + 1024B + lane*16B.
    {
#pragma unroll
        for (int i = 0; i < 2; ++i) {
            const int tau = i * NT + t;           // tile id, 1024 tiles of 4k x 4n
            const int ng = tau & 31, kg = tau >> 5;
            const int n0 = ng * 4, k0 = kg * 4;
            f4 r[4];
#pragma unroll
            for (int e = 0; e < 4; ++e)
                r[e] = *reinterpret_cast<const f4*>(W1 + (k0 + e) * HID + n0);
            const int p   = (k0 >> 5) * 8 + (n0 >> 4);
            const int j0h = (k0 & 7) >> 1;         // 0 or 2 (dword offset of j-block)
            const int l0  = ((k0 >> 3) & 3) * 16;
#pragma unroll
            for (int c = 0; c < 4; ++c) {
                const int lane0 = l0 + (n0 & 15) + c;
                unsigned hs[4], ls[4];
#pragma unroll
                for (int e = 0; e < 4; ++e) {
                    float v = r[e][c];
                    __bf16 hb = (__bf16)v;
                    __bf16 lb = (__bf16)(v - (float)hb);
                    hs[e] = bf2us(hb); ls[e] = bf2us(lb);
                }
                uint2 sh, sl;
                sh.x = hs[0] | (hs[1] << 16); sh.y = hs[2] | (hs[3] << 16);
                sl.x = ls[0] | (ls[1] << 16); sl.y = ls[2] | (ls[3] << 16);
                const int base = p * FS + lane0 * 4 + j0h;
                *reinterpret_cast<uint2*>(&HpT[base])       = sh;
                *reinterpret_cast<uint2*>(&HpT[base + 256]) = sl;
            }
        }
    }
#pragma unroll
    for (int i = 0; i < 4; ++i)
        atomicAdd(&AdjN[ed[i] * AS + (es[i] >> 3)], 1u << ((es[i] & 7) * 4));
    __syncthreads();   // W1 frags + adjacency complete

    // ---- t<128: deg via nibble row-sum -> rsl; then diagonal +1 (own row) ----
    if (t < NPG) {
        unsigned* row = &AdjN[t * AS];
        unsigned sum = 0;
#pragma unroll
        for (int w = 0; w < 16; ++w) {
            unsigned u = row[w];
            unsigned b = (u & 0x0F0F0F0Fu) + ((u >> 4) & 0x0F0F0F0Fu);
            sum += (b * 0x01010101u) >> 24;
        }
        rsl[t] = rsqrtf((float)(sum + 1));
        row[t >> 3] += 1u << ((t & 7) * 4);
    }

    // ---- GEMM1 via MFMA: H0 = (xh+xl)@(wh+wl), wave's 4 ct blocks only ----
    // lo*lo term dropped (~3e-7 per dot, negligible).
    f4 acc[2][4];
#pragma unroll
    for (int rt = 0; rt < 2; ++rt)
#pragma unroll
        for (int c = 0; c < 4; ++c) {
            acc[rt][c].x = 0.f; acc[rt][c].y = 0.f;
            acc[rt][c].z = 0.f; acc[rt][c].w = 0.f;
        }
#pragma unroll
    for (int ks = 0; ks < 4; ++ks)
#pragma unroll
        for (int c = 0; c < 4; ++c) {
            const int ctg = ch * 4 + c;
            const unsigned* fp = &HpT[(ks * 8 + ctg) * FS + lane * 4];
            bfrag bh = *reinterpret_cast<const bfrag*>(fp);
            bfrag bl = *reinterpret_cast<const bfrag*>(fp + 256);
#pragma unroll
            for (int rt = 0; rt < 2; ++rt) {
                const int r = rt * 4 + ks;
                acc[rt][c] = __builtin_amdgcn_mfma_f32_16x16x32_bf16(ah[r], bh, acc[rt][c], 0, 0, 0);
                acc[rt][c] = __builtin_amdgcn_mfma_f32_16x16x32_bf16(al[r], bh, acc[rt][c], 0, 0, 0);
                acc[rt][c] = __builtin_amdgcn_mfma_f32_16x16x32_bf16(ah[r], bl, acc[rt][c], 0, 0, 0);
            }
        }
    __syncthreads();   // all frag reads done; rsl ready -> HpT reusable for H0'

    // ---- epilogue: H0' = rs*H0, feature-major rows [hi x128][lo x128] ----
#pragma unroll
    for (int rt = 0; rt < 2; ++rt) {
        const int mb = m0 + rt * 16 + quad * 4;
        f4 rs4 = *reinterpret_cast<const f4*>(&rsl[mb]);
#pragma unroll
        for (int c = 0; c < 4; ++c) {
            const int ctg = ch * 4 + c;
            unsigned hs[4], ls[4];
#pragma unroll
            for (int reg = 0; reg < 4; ++reg) {
                float v = acc[rt][c][reg] * rs4[reg];
                __bf16 hb = (__bf16)v;
                __bf16 lb = (__bf16)(v - (float)hb);
                hs[reg] = bf2us(hb); ls[reg] = bf2us(lb);
            }
            uint2 sh, sl;
            sh.x = hs[0] | (hs[1] << 16); sh.y = hs[2] | (hs[3] << 16);
            sl.x = ls[0] | (ls[1] << 16); sl.y = ls[2] | (ls[3] << 16);
            const int rb = (ctg * 16 + n16) * HS + (mb >> 1);
            *reinterpret_cast<uint2*>(&HpT[rb])      = sh;
            *reinterpret_cast<uint2*>(&HpT[rb + 64]) = sl;
        }
    }
    __syncthreads();

    // small vectors (L2-hot, latency hidden under agg MFMAs)
    float b1v[4], wsv[4];
#pragma unroll
    for (int c = 0; c < 4; ++c) {
        b1v[c] = b1[(ch * 4 + c) * 16 + n16];
        wsv[c] = Ws[(ch * 4 + c) * 16 + n16];
    }
    const float bsv = bsp[0];

    // ---- conv1 aggregation via MFMA: agg = (Adj+I) @ H0'(hi+lo) ----
    f4 hacc[2][4];
#pragma unroll
    for (int rt = 0; rt < 2; ++rt)
#pragma unroll
        for (int c = 0; c < 4; ++c) {
            hacc[rt][c].x = 0.f; hacc[rt][c].y = 0.f;
            hacc[rt][c].z = 0.f; hacc[rt][c].w = 0.f;
        }
#pragma unroll
    for (int ks = 0; ks < 4; ++ks) {
        bfrag af[2];
#pragma unroll
        for (int rt = 0; rt < 2; ++rt) {
            unsigned w = AdjN[(m0 + rt * 16 + n16) * AS + ks * 4 + quad];
#pragma unroll
            for (int j = 0; j < 8; ++j)
                af[rt][j] = (__bf16)(float)((w >> (4 * j)) & 15u);
        }
#pragma unroll
        for (int c = 0; c < 4; ++c) {
            const int ctg = ch * 4 + c;
            const unsigned* bp = &HpT[(ctg * 16 + n16) * HS + ks * 16 + quad * 4];
            bfrag bh = *reinterpret_cast<const bfrag*>(bp);
            bfrag bl = *reinterpret_cast<const bfrag*>(bp + 64);
#pragma unroll
            for (int rt = 0; rt < 2; ++rt) {
                hacc[rt][c] = __builtin_amdgcn_mfma_f32_16x16x32_bf16(af[rt], bh, hacc[rt][c], 0, 0, 0);
                hacc[rt][c] = __builtin_amdgcn_mfma_f32_16x16x32_bf16(af[rt], bl, hacc[rt][c], 0, 0, 0);
            }
        }
    }

    // epilogue in regs: h = relu(rs*agg + b1)   (h stays in registers)
    f4 rsm[2];
#pragma unroll
    for (int rt = 0; rt < 2; ++rt)
        rsm[rt] = *reinterpret_cast<const f4*>(&rsl[m0 + rt * 16 + quad * 4]);
#pragma unroll
    for (int rt = 0; rt < 2; ++rt)
#pragma unroll
        for (int c = 0; c < 4; ++c)
#pragma unroll
            for (int reg = 0; reg < 4; ++reg)
                hacc[rt][c][reg] = fmaxf(hacc[rt][c][reg] * rsm[rt][reg] + b1v[c], 0.f);

    // ---- spl partial = rs * (h @ Ws over this col-half); shfl over n16 ----
    {
        float dot[2][4];
#pragma unroll
        for (int rt = 0; rt < 2; ++rt)
#pragma unroll
            for (int reg = 0; reg < 4; ++reg) dot[rt][reg] = 0.f;
#pragma unroll
        for (int c = 0; c < 4; ++c)
#pragma unroll
            for (int rt = 0; rt < 2; ++rt)
#pragma unroll
                for (int reg = 0; reg < 4; ++reg)
                    dot[rt][reg] += hacc[rt][c][reg] * wsv[c];
#pragma unroll
        for (int d = 1; d < 16; d <<= 1)
#pragma unroll
            for (int rt = 0; rt < 2; ++rt)
#pragma unroll
                for (int reg = 0; reg < 4; ++reg)
                    dot[rt][reg] += __shfl_xor(dot[rt][reg], d, 64);
        if (n16 == 0) {
#pragma unroll
            for (int rt = 0; rt < 2; ++rt)
#pragma unroll
                for (int reg = 0; reg < 4; ++reg)
                    spl[ch * NPG + m0 + rt * 16 + quad * 4 + reg] = rsm[rt][reg] * dot[rt][reg];
        }
    }
    __syncthreads();   // spl partials ready; HpT reusable for Wlin

    // ---- score = rs * ((Adj+I) @ (spl0+spl1)) + bs  (threads 0-127)
    // ---- overlapped: threads 128-383 stage Wlin -> HpT (hides L2 fetch) ----
    if (t < NPG) {
        const unsigned* row = &AdjN[t * AS];
        const float* sp0 = spl;
        const float* sp1 = spl + NPG;
        float sc = 0.f;
#pragma unroll
        for (int w = 0; w < 16; ++w) {
            unsigned u = row[w];
            const int b8 = w * 8;
            sc += (float)(u & 15u)         * (sp0[b8]     + sp1[b8])
                + (float)((u >> 4)  & 15u) * (sp0[b8 + 1] + sp1[b8 + 1])
                + (float)((u >> 8)  & 15u) * (sp0[b8 + 2] + sp1[b8 + 2])
                + (float)((u >> 12) & 15u) * (sp0[b8 + 3] + sp1[b8 + 3])
                + (float)((u >> 16) & 15u) * (sp0[b8 + 4] + sp1[b8 + 4])
                + (float)((u >> 20) & 15u) * (sp0[b8 + 5] + sp1[b8 + 5])
                + (float)((u >> 24) & 15u) * (sp0[b8 + 6] + sp1[b8 + 6])
                + (float)(u >> 28)         * (sp0[b8 + 7] + sp1[b8 + 7]);
        }
        scl[t] = rsl[t] * sc + bsv;
    } else if (t < 384) {
        const int ts = t - NPG;   // 0..255
        const f4* WL4 = reinterpret_cast<const f4*>(Wlin);
#pragma unroll
        for (int i = 0; i < 16; ++i) {
            const int fd = i * 256 + ts;          // 4096 f4 = 64 KB, linear copy
            *reinterpret_cast<f4*>(&HpT[fd * 4]) = WL4[fd];
        }
    }
    __syncthreads();

    // ---- top-K by exact rank (stable), fully unrolled float4 broadcasts ----
    if (t < NPG) {
        float v = scl[t];
        int rank = 0;
#pragma unroll
        for (int j4 = 0; j4 < 32; ++j4) {
            float4 u = *reinterpret_cast<const float4*>(&scl[j4 * 4]);
            const int jb = j4 * 4;
            rank += (u.x > v || (u.x == v && jb     < t)) ? 1 : 0;
            rank += (u.y > v || (u.y == v && jb + 1 < t)) ? 1 : 0;
            rank += (u.z > v || (u.z == v && jb + 2 < t)) ? 1 : 0;
            rank += (u.w > v || (u.w == v && jb + 3 < t)) ? 1 : 0;
        }
        wgt[t] = (rank < KSEL) ? tanhf(v) * (1.0f / KSEL) : 0.f;
    }
    __syncthreads();

    // ---- pooled[c] = sum_m wgt[m]*h[m][c] from registers; shfl over quads ----
    {
        float p[4];
        f4 wm[2];
#pragma unroll
        for (int rt = 0; rt < 2; ++rt)
            wm[rt] = *reinterpret_cast<const f4*>(&wgt[m0 + rt * 16 + quad * 4]);
#pragma unroll
        for (int c = 0; c < 4; ++c) {
            float s = 0.f;
#pragma unroll
            for (int rt = 0; rt < 2; ++rt)
#pragma unroll
                for (int reg = 0; reg < 4; ++reg)
                    s += wm[rt][reg] * hacc[rt][c][reg];
            p[c] = s;
        }
#pragma unroll
        for (int d = 16; d < 64; d <<= 1)
#pragma unroll
            for (int c = 0; c < 4; ++c)
                p[c] += __shfl_xor(p[c], d, 64);
        if (quad == 0) {
#pragma unroll
            for (int c = 0; c < 4; ++c)
                pp[rt4 * HID + (ch * 4 + c) * 16 + n16] = p[c];
        }
    }
    __syncthreads();
    if (t < NPG)
        scl[t] = pp[t] + pp[HID + t] + pp[2 * HID + t] + pp[3 * HID + t];  // pooled
    __syncthreads();

    // ---- out = pooled @ Wlin + blin, Wlin in LDS (staged under score phase)
    //      16 k-groups x 32 col-quads across all 512 threads ----
    {
        const int c4 = (t & 31) * 4, rg = t >> 5;   // rg in [0,16)
        f4 s4; s4.x = 0.f; s4.y = 0.f; s4.z = 0.f; s4.w = 0.f;
#pragma unroll
        for (int kk = 0; kk < 8; ++kk) {
            const int k = rg * 8 + kk;
            const f4 w = *reinterpret_cast<const f4*>(&HpT[k * HID + c4]);
            const float sk = scl[k];
            s4.x += sk * w.x; s4.y += sk * w.y;
            s4.z += sk * w.z; s4.w += sk * w.w;
        }
        float* part = reinterpret_cast<float*>(AdjN);   // AdjN dead after score
        *reinterpret_cast<f4*>(&part[rg * HID + c4]) = s4;
    }
    __syncthreads();
    if (t < NPG) {
        const float* part = reinterpret_cast<const float*>(AdjN);
        float s = blin[t];
#pragma unroll
        for (int r = 0; r < 16; ++r) s += part[r * HID + t];
        out[(long)g * HID + t] = s;
    }
}

extern "C" void kernel_launch(void* const* d_in, const int* in_sizes, int n_in,
                              void* d_out, int out_size, void* d_ws, size_t ws_size,
                              hipStream_t stream) {
    const float* x    = (const float*)d_in[0];
    const int*   ei   = (const int*)  d_in[1];
    const float* W1   = (const float*)d_in[3];
    const float* b1   = (const float*)d_in[4];
    const float* Ws   = (const float*)d_in[5];
    const float* bs   = (const float*)d_in[6];
    const float* Wlin = (const float*)d_in[7];
    const float* blin = (const float*)d_in[8];
    float* out = (float*)d_out;

    const int E = in_sizes[1] / 2;          // 1048576
    const int nnodes = in_sizes[0] / HID;   // 65536
    const int B = nnodes / NPG;             // 512
    const int epg = E / B;                  // 2048

    sagpool_fused<<<B, NT, 0, stream>>>(x, ei, ei + E, W1, b1, Ws, bs,
                                        Wlin, blin, out, epg);
}

// Round 4
// 109.099 us; speedup vs baseline: 1.0409x; 1.0409x over previous
//
#include <hip/hip_runtime.h>
#include <math.h>

#define NPG  128
#define HID  128
#define KSEL 64
#define NT   256   // 4 waves/block; LDS 80,384 B -> 2 blocks/CU
#define HS   132   // H0' row stride in dwords: [128 hi us][128 lo us][pad]; 132%32==4
#define AS   17    // AdjN row stride in dwords (odd -> spread banks)
#define FS   516   // W1 frag-pair stride in dwords: [hi 256 dw][lo 256 dw][pad 4]

typedef __attribute__((ext_vector_type(8))) __bf16 bfrag;   // 8 bf16 = 4 VGPRs
typedef __attribute__((ext_vector_type(4))) float f4;

static __device__ __forceinline__ unsigned short bf2us(__bf16 b) {
    union { unsigned short s; __bf16 b; } x; x.b = b; return x.s;
}

// Single fused kernel, one block per graph, 4 waves (NT=256: the NT=512 variant
// regressed -5.3us -- VGPR cap 128 forced spills; occupancy is LDS-capped anyway).
// LDS phase plan for HpT region (67,584 B):
//   phase A: W1 bf16 MFMA B-fragments, hi-block + lo-block per frag-pair
//            (separated, NOT bit-packed -> ds_read_b128 is directly a bfrag)
//   phase B: H0' (rs-scaled x@W1) feature-major, per row [hi x128][lo x128]
//   phase C: Wlin staged linear [k][n] (64 KB) for the output GEMM
__global__ __launch_bounds__(NT, 2) void sagpool_fused(
    const float* __restrict__ x,
    const int*   __restrict__ esrc,
    const int*   __restrict__ edst,
    const float* __restrict__ W1,
    const float* __restrict__ b1,
    const float* __restrict__ Ws,
    const float* __restrict__ bsp,
    const float* __restrict__ Wlin,
    const float* __restrict__ blin,
    float* __restrict__ out,
    int epg)
{
    __shared__ __align__(16) unsigned HpT[HID * HS];   // 67,584 B (see phase plan)
    __shared__ __align__(16) unsigned AdjN[NPG * AS];  // nibble counts; reused as out-partials
    __shared__ __align__(16) float rsl[NPG];
    __shared__ __align__(16) float spl[NPG];
    __shared__ __align__(16) float scl[NPG];           // scores
    __shared__ __align__(16) float wgt[NPG];
    __shared__ __align__(16) float pp[4 * HID];

    const int g = blockIdx.x, t = threadIdx.x;
    const int node0 = g * NPG;
    const long e0 = (long)g * epg;
    const int lane = t & 63, wv = t >> 6;         // wv in [0,4)
    const int n16 = lane & 15, quad = lane >> 4;
    const int m0 = wv * 32;                       // this wave's 32-row tile

    // ---- early independent global loads: edges, x rows, W1 (issue-early) ----
    int es[8], ed[8];
#pragma unroll
    for (int i = 0; i < 8; ++i) {
        int e = i * NT + t;
        es[i] = esrc[e0 + e] - node0;
        ed[i] = edst[e0 + e] - node0;
    }
    f4 xr[16];   // raw x rows for this wave's 32-row tile
    {
        const float* xw = x + (long)(node0 + m0) * HID;
#pragma unroll
        for (int rt = 0; rt < 2; ++rt)
#pragma unroll
            for (int ks = 0; ks < 4; ++ks) {
                const float* xp = xw + (rt * 16 + n16) * HID + ks * 32 + quad * 8;
                xr[(rt * 4 + ks) * 2]     = *reinterpret_cast<const f4*>(xp);
                xr[(rt * 4 + ks) * 2 + 1] = *reinterpret_cast<const f4*>(xp + 4);
            }
    }
    // W1 loads issued NOW; latency hides under the x->bf16 hi/lo convert below.
    f4 w1r[4][4];
#pragma unroll
    for (int i = 0; i < 4; ++i) {
        const int tau = i * NT + t;           // tile id, 1024 tiles of 4k x 4n
        const int ng = tau & 31, kg = tau >> 5;
        const float* wp = W1 + (kg * 4) * HID + ng * 4;
#pragma unroll
        for (int e = 0; e < 4; ++e)
            w1r[i][e] = *reinterpret_cast<const f4*>(wp + e * HID);
    }
    float b1v[8], wsv[8];
#pragma unroll
    for (int ct = 0; ct < 8; ++ct) {
        b1v[ct] = b1[ct * 16 + n16];
        wsv[ct] = Ws[ct * 16 + n16];
    }
    const float bsv = bsp[0];

    // ---- zero AdjN (no load deps; issues early) ----
    for (int i = t; i < NPG * AS; i += NT) AdjN[i] = 0u;

    // ---- convert x -> A-frags (W1 loads in flight under this VALU block) ----
    bfrag ah[8], al[8];
#pragma unroll
    for (int r = 0; r < 8; ++r)
#pragma unroll
        for (int j = 0; j < 8; ++j) {
            float v = (j < 4) ? xr[2 * r][j] : xr[2 * r + 1][j - 4];
            __bf16 hb = (__bf16)v;
            ah[r][j] = hb;
            al[r][j] = (__bf16)(v - (float)hb);
        }
    __syncthreads();

    // ---- phase: stage W1 -> LDS frag-pairs (hi-block|lo-block) + edge atomics ----
    // Fragment (ks,ct): lane holds B[k=ks*32+quad*8+j][n=ct*16+n16] as 8 bf16 (16B);
    // hi at pairbase + lane*16B, lo at pairbase + 1024B + lane*16B.
    {
#pragma unroll
        for (int i = 0; i < 4; ++i) {
            const int tau = i * NT + t;
            const int ng = tau & 31, kg = tau >> 5;
            const int n0 = ng * 4, k0 = kg * 4;
            const int p   = (k0 >> 5) * 8 + (n0 >> 4);
            const int j0h = (k0 & 7) >> 1;         // 0 or 2 (dword offset of j-block)
            const int l0  = ((k0 >> 3) & 3) * 16;
#pragma unroll
            for (int c = 0; c < 4; ++c) {
                const int lane0 = l0 + (n0 & 15) + c;
                unsigned hs[4], ls[4];
#pragma unroll
                for (int e = 0; e < 4; ++e) {
                    float v = w1r[i][e][c];
                    __bf16 hb = (__bf16)v;
                    __bf16 lb = (__bf16)(v - (float)hb);
                    hs[e] = bf2us(hb); ls[e] = bf2us(lb);
                }
                uint2 sh, sl;
                sh.x = hs[0] | (hs[1] << 16); sh.y = hs[2] | (hs[3] << 16);
                sl.x = ls[0] | (ls[1] << 16); sl.y = ls[2] | (ls[3] << 16);
                const int base = p * FS + lane0 * 4 + j0h;
                *reinterpret_cast<uint2*>(&HpT[base])       = sh;
                *reinterpret_cast<uint2*>(&HpT[base + 256]) = sl;
            }
        }
    }
#pragma unroll
    for (int i = 0; i < 8; ++i)
        atomicAdd(&AdjN[ed[i] * AS + (es[i] >> 3)], 1u << ((es[i] & 7) * 4));
    __syncthreads();   // W1 frags + adjacency complete

    // ---- t<128: deg via nibble row-sum -> rsl; then diagonal +1 (own row) ----
    if (t < NPG) {
        unsigned* row = &AdjN[t * AS];
        unsigned sum = 0;
#pragma unroll
        for (int w = 0; w < 16; ++w) {
            unsigned u = row[w];
            unsigned b = (u & 0x0F0F0F0Fu) + ((u >> 4) & 0x0F0F0F0Fu);
            sum += (b * 0x01010101u) >> 24;
        }
        rsl[t] = rsqrtf((float)(sum + 1));
        row[t >> 3] += 1u << ((t & 7) * 4);
    }

    // ---- GEMM1 via MFMA: H0 = (xh+xl)@(wh+wl), B-frags direct from LDS ----
    // lo*lo term dropped (~3e-7 per dot, negligible).
    f4 acc[2][8];
#pragma unroll
    for (int rt = 0; rt < 2; ++rt)
#pragma unroll
        for (int ct = 0; ct < 8; ++ct) {
            acc[rt][ct].x = 0.f; acc[rt][ct].y = 0.f;
            acc[rt][ct].z = 0.f; acc[rt][ct].w = 0.f;
        }
#pragma unroll
    for (int ks = 0; ks < 4; ++ks)
#pragma unroll
        for (int ct = 0; ct < 8; ++ct) {
            const unsigned* fp = &HpT[(ks * 8 + ct) * FS + lane * 4];
            bfrag bh = *reinterpret_cast<const bfrag*>(fp);
            bfrag bl = *reinterpret_cast<const bfrag*>(fp + 256);
#pragma unroll
            for (int rt = 0; rt < 2; ++rt) {
                const int r = rt * 4 + ks;
                acc[rt][ct] = __builtin_amdgcn_mfma_f32_16x16x32_bf16(ah[r], bh, acc[rt][ct], 0, 0, 0);
                acc[rt][ct] = __builtin_amdgcn_mfma_f32_16x16x32_bf16(al[r], bh, acc[rt][ct], 0, 0, 0);
                acc[rt][ct] = __builtin_amdgcn_mfma_f32_16x16x32_bf16(ah[r], bl, acc[rt][ct], 0, 0, 0);
            }
        }
    __syncthreads();   // all frag reads done; rsl ready -> HpT reusable for H0'

    // ---- epilogue: H0' = rs*H0, feature-major rows [hi x128][lo x128] ----
#pragma unroll
    for (int rt = 0; rt < 2; ++rt) {
        const int mb = m0 + rt * 16 + quad * 4;
        f4 rs4 = *reinterpret_cast<const f4*>(&rsl[mb]);
#pragma unroll
        for (int ct = 0; ct < 8; ++ct) {
            unsigned hs[4], ls[4];
#pragma unroll
            for (int reg = 0; reg < 4; ++reg) {
                float v = acc[rt][ct][reg] * rs4[reg];
                __bf16 hb = (__bf16)v;
                __bf16 lb = (__bf16)(v - (float)hb);
                hs[reg] = bf2us(hb); ls[reg] = bf2us(lb);
            }
            uint2 sh, sl;
            sh.x = hs[0] | (hs[1] << 16); sh.y = hs[2] | (hs[3] << 16);
            sl.x = ls[0] | (ls[1] << 16); sl.y = ls[2] | (ls[3] << 16);
            const int rb = (ct * 16 + n16) * HS + (mb >> 1);
            *reinterpret_cast<uint2*>(&HpT[rb])      = sh;
            *reinterpret_cast<uint2*>(&HpT[rb + 64]) = sl;
        }
    }
    __syncthreads();

    // ---- conv1 aggregation via MFMA: agg = (Adj+I) @ H0'(hi+lo) ----
    f4 hacc[2][8];
#pragma unroll
    for (int mt = 0; mt < 2; ++mt)
#pragma unroll
        for (int ct = 0; ct < 8; ++ct) {
            hacc[mt][ct].x = 0.f; hacc[mt][ct].y = 0.f;
            hacc[mt][ct].z = 0.f; hacc[mt][ct].w = 0.f;
        }
#pragma unroll
    for (int ks = 0; ks < 4; ++ks) {
        bfrag af[2];
#pragma unroll
        for (int mt = 0; mt < 2; ++mt) {
            unsigned w = AdjN[(m0 + mt * 16 + n16) * AS + ks * 4 + quad];
#pragma unroll
            for (int j = 0; j < 8; ++j)
                af[mt][j] = (__bf16)(float)((w >> (4 * j)) & 15u);
        }
#pragma unroll
        for (int ct = 0; ct < 8; ++ct) {
            const unsigned* bp = &HpT[(ct * 16 + n16) * HS + ks * 16 + quad * 4];
            bfrag bh = *reinterpret_cast<const bfrag*>(bp);
            bfrag bl = *reinterpret_cast<const bfrag*>(bp + 64);
#pragma unroll
            for (int mt = 0; mt < 2; ++mt) {
                hacc[mt][ct] = __builtin_amdgcn_mfma_f32_16x16x32_bf16(af[mt], bh, hacc[mt][ct], 0, 0, 0);
                hacc[mt][ct] = __builtin_amdgcn_mfma_f32_16x16x32_bf16(af[mt], bl, hacc[mt][ct], 0, 0, 0);
            }
        }
    }

    // epilogue in regs: h = relu(rs*agg + b1)   (h stays in registers)
    f4 rsm[2];
#pragma unroll
    for (int mt = 0; mt < 2; ++mt)
        rsm[mt] = *reinterpret_cast<const f4*>(&rsl[m0 + mt * 16 + quad * 4]);
#pragma unroll
    for (int mt = 0; mt < 2; ++mt)
#pragma unroll
        for (int ct = 0; ct < 8; ++ct)
#pragma unroll
            for (int reg = 0; reg < 4; ++reg)
                hacc[mt][ct][reg] = fmaxf(hacc[mt][ct][reg] * rsm[mt][reg] + b1v[ct], 0.f);

    // ---- spl' = rs * (h @ Ws): per-row dot, shfl_xor reduce over n-group ----
    {
        float dot[2][4];
#pragma unroll
        for (int mt = 0; mt < 2; ++mt)
#pragma unroll
            for (int reg = 0; reg < 4; ++reg) dot[mt][reg] = 0.f;
#pragma unroll
        for (int ct = 0; ct < 8; ++ct)
#pragma unroll
            for (int mt = 0; mt < 2; ++mt)
#pragma unroll
                for (int reg = 0; reg < 4; ++reg)
                    dot[mt][reg] += hacc[mt][ct][reg] * wsv[ct];
#pragma unroll
        for (int d = 1; d < 16; d <<= 1)
#pragma unroll
            for (int mt = 0; mt < 2; ++mt)
#pragma unroll
                for (int reg = 0; reg < 4; ++reg)
                    dot[mt][reg] += __shfl_xor(dot[mt][reg], d, 64);
        if (n16 == 0) {
#pragma unroll
            for (int mt = 0; mt < 2; ++mt)
#pragma unroll
                for (int reg = 0; reg < 4; ++reg)
                    spl[m0 + mt * 16 + quad * 4 + reg] = rsm[mt][reg] * dot[mt][reg];
        }
    }
    __syncthreads();   // spl ready; all agg frag reads done -> HpT reusable for Wlin

    // ---- score = rs * ((Adj+I) @ spl') + bs  (waves 0-1)
    // ---- overlapped: waves 2-3 stage Wlin -> HpT (hides the L2 fetch) ----
    if (t < NPG) {
        const unsigned* row = &AdjN[t * AS];
        float sc = 0.f;
#pragma unroll
        for (int w = 0; w < 16; ++w) {
            unsigned u = row[w];
            const float* sp = &spl[w * 8];
            sc += (float)(u & 15u)         * sp[0] + (float)((u >> 4)  & 15u) * sp[1]
                + (float)((u >> 8)  & 15u) * sp[2] + (float)((u >> 12) & 15u) * sp[3]
                + (float)((u >> 16) & 15u) * sp[4] + (float)((u >> 20) & 15u) * sp[5]
                + (float)((u >> 24) & 15u) * sp[6] + (float)(u >> 28)         * sp[7];
        }
        scl[t] = rsl[t] * sc + bsv;
    } else {
        const int tt = t - NPG;   // 0..127
        const f4* WL4 = reinterpret_cast<const f4*>(Wlin);
        for (int ib = 0; ib < 4; ++ib) {
            f4 w[8];
#pragma unroll
            for (int u = 0; u < 8; ++u)
                w[u] = WL4[(ib * 8 + u) * 128 + tt];
#pragma unroll
            for (int u = 0; u < 8; ++u)
                *reinterpret_cast<f4*>(&HpT[((ib * 8 + u) * 128 + tt) * 4]) = w[u];
        }
    }
    __syncthreads();

    // ---- top-K by exact rank (stable), fully unrolled float4 broadcasts ----
    if (t < NPG) {
        float v = scl[t];
        int rank = 0;
#pragma unroll
        for (int j4 = 0; j4 < 32; ++j4) {
            float4 u = *reinterpret_cast<const float4*>(&scl[j4 * 4]);
            const int jb = j4 * 4;
            rank += (u.x > v || (u.x == v && jb     < t)) ? 1 : 0;
            rank += (u.y > v || (u.y == v && jb + 1 < t)) ? 1 : 0;
            rank += (u.z > v || (u.z == v && jb + 2 < t)) ? 1 : 0;
            rank += (u.w > v || (u.w == v && jb + 3 < t)) ? 1 : 0;
        }
        wgt[t] = (rank < KSEL) ? tanhf(v) * (1.0f / KSEL) : 0.f;
    }
    __syncthreads();

    // ---- pooled[c] = sum_m wgt[m]*h[m][c] from registers; shfl over quads ----
    {
        float p[8];
        f4 wm[2];
#pragma unroll
        for (int mt = 0; mt < 2; ++mt)
            wm[mt] = *reinterpret_cast<const f4*>(&wgt[m0 + mt * 16 + quad * 4]);
#pragma unroll
        for (int ct = 0; ct < 8; ++ct) {
            float s = 0.f;
#pragma unroll
            for (int mt = 0; mt < 2; ++mt)
#pragma unroll
                for (int reg = 0; reg < 4; ++reg)
                    s += wm[mt][reg] * hacc[mt][ct][reg];
            p[ct] = s;
        }
#pragma unroll
        for (int d = 16; d < 64; d <<= 1)
#pragma unroll
            for (int ct = 0; ct < 8; ++ct)
                p[ct] += __shfl_xor(p[ct], d, 64);
        if (quad == 0) {
#pragma unroll
            for (int ct = 0; ct < 8; ++ct)
                pp[wv * HID + ct * 16 + n16] = p[ct];
        }
    }
    __syncthreads();   // pp partials ready

    // ---- out = pooled @ Wlin + blin, Wlin in LDS; pooled summed from the 4
    //      per-wave partials on the fly (broadcast reads -> saves a barrier +
    //      a t<128-only combine phase) ----
    {
        const int c4 = (t & 31) * 4, rg = t >> 5;   // rg in [0,8)
        f4 s4; s4.x = 0.f; s4.y = 0.f; s4.z = 0.f; s4.w = 0.f;
#pragma unroll 8
        for (int kk = 0; kk < 16; ++kk) {
            const int k = rg * 16 + kk;
            const float sk = pp[k] + pp[HID + k] + pp[2 * HID + k] + pp[3 * HID + k];
            const f4 w = *reinterpret_cast<const f4*>(&HpT[k * HID + c4]);
            s4.x += sk * w.x; s4.y += sk * w.y;
            s4.z += sk * w.z; s4.w += sk * w.w;
        }
        float* part = reinterpret_cast<float*>(AdjN);   // AdjN dead after score
        *reinterpret_cast<f4*>(&part[rg * HID + c4]) = s4;
    }
    __syncthreads();
    if (t < NPG) {
        const float* part = reinterpret_cast<const float*>(AdjN);
        float s = blin[t];
#pragma unroll
        for (int r = 0; r < 8; ++r) s += part[r * HID + t];
        out[(long)g * HID + t] = s;
    }
}

extern "C" void kernel_launch(void* const* d_in, const int* in_sizes, int n_in,
                              void* d_out, int out_size, void* d_ws, size_t ws_size,
                              hipStream_t stream) {
    const float* x    = (const float*)d_in[0];
    const int*   ei   = (const int*)  d_in[1];
    const float* W1   = (const float*)d_in[3];
    const float* b1   = (const float*)d_in[4];
    const float* Ws   = (const float*)d_in[5];
    const float* bs   = (const float*)d_in[6];
    const float* Wlin = (const float*)d_in[7];
    const float* blin = (const float*)d_in[8];
    float* out = (float*)d_out;

    const int E = in_sizes[1] / 2;          // 1048576
    const int nnodes = in_sizes[0] / HID;   // 65536
    const int B = nnodes / NPG;             // 512
    const int epg = E / B;                  // 2048

    sagpool_fused<<<B, NT, 0, stream>>>(x, ei, ei + E, W1, b1, Ws, bs,
                                        Wlin, blin, out, epg);
}

// Round 5
// 108.709 us; speedup vs baseline: 1.0447x; 1.0036x over previous
//
#include <hip/hip_runtime.h>
#include <math.h>

#define NPG  128
#define HID  128
#define KSEL 64
#define NT   256   // 4 waves/block; LDS 79,872 B -> 2 blocks/CU
#define HS   132   // H0' row stride in dwords: [128 hi us][128 lo us][pad]; 132%32==4
#define AS   17    // AdjN row stride in dwords (odd -> spread banks)
#define FS   516   // W1 frag-pair stride in dwords: [hi 256 dw][lo 256 dw][pad 4]

typedef __attribute__((ext_vector_type(8))) __bf16 bfrag;   // 8 bf16 = 4 VGPRs
typedef __attribute__((ext_vector_type(4))) float f4;

static __device__ __forceinline__ unsigned short bf2us(__bf16 b) {
    union { unsigned short s; __bf16 b; } x; x.b = b; return x.s;
}
// tanh(v) = 1 - 2/(e^{2v}+1); exp inf/0 endpoints give exact +-1. ~5 VALU ops.
static __device__ __forceinline__ float fast_tanh(float v) {
    float e = __expf(2.f * v);
    return 1.f - 2.f * __builtin_amdgcn_rcpf(e + 1.f);
}

// Single fused kernel, one block per graph, 4 waves (NT=512 regressed: VGPR spills).
// R5 changes: wave-parallel deg/rs (in-reg via ds_bpermute, no idle-wave phase),
// GEMM1/agg ct-pair-outer with pack/relu/dot in MFMA shadow, barrier-free
// wave-redundant top-k (wgt in registers), batched Wlin staging.
// LDS phase plan for HpT region (67,584 B):
//   phase A: W1 bf16 B-frags, hi-block + lo-block per frag-pair (ds_read_b128 = bfrag)
//   phase B: H0' (rs-scaled x@W1) feature-major, per row [hi x128][lo x128]
//   phase C: Wlin staged linear [k][n] (64 KB) for the output GEMM
__global__ __launch_bounds__(NT, 2) void sagpool_fused(
    const float* __restrict__ x,
    const int*   __restrict__ esrc,
    const int*   __restrict__ edst,
    const float* __restrict__ W1,
    const float* __restrict__ b1,
    const float* __restrict__ Ws,
    const float* __restrict__ bsp,
    const float* __restrict__ Wlin,
    const float* __restrict__ blin,
    float* __restrict__ out,
    int epg)
{
    __shared__ __align__(16) unsigned HpT[HID * HS];   // 67,584 B (see phase plan)
    __shared__ __align__(16) unsigned AdjN[NPG * AS];  // nibble counts; reused as out-partials
    __shared__ __align__(16) float rsl[NPG];
    __shared__ __align__(16) float spl[NPG];
    __shared__ __align__(16) float scl[NPG];           // scores
    __shared__ __align__(16) float pp[4 * HID];

    const int g = blockIdx.x, t = threadIdx.x;
    const int node0 = g * NPG;
    const long e0 = (long)g * epg;
    const int lane = t & 63, wv = t >> 6;         // wv in [0,4)
    const int n16 = lane & 15, quad = lane >> 4;
    const int l2 = lane & 31, half = lane >> 5;
    const int m0 = wv * 32;                       // this wave's 32-row tile

    // ---- early independent global loads: edges, x rows, small vectors ----
    int es[8], ed[8];
#pragma unroll
    for (int i = 0; i < 8; ++i) {
        int e = i * NT + t;
        es[i] = esrc[e0 + e] - node0;
        ed[i] = edst[e0 + e] - node0;
    }
    bfrag ah[8], al[8];   // A-frags for 2 row-tiles x 4 k-slices
    {
        const float* xw = x + (long)(node0 + m0) * HID;
#pragma unroll
        for (int rt = 0; rt < 2; ++rt)
#pragma unroll
            for (int ks = 0; ks < 4; ++ks) {
                const float* xr = xw + (rt * 16 + n16) * HID + ks * 32 + quad * 8;
                float4 a = *reinterpret_cast<const float4*>(xr);
                float4 b = *reinterpret_cast<const float4*>(xr + 4);
                float vv[8] = {a.x, a.y, a.z, a.w, b.x, b.y, b.z, b.w};
                const int r = rt * 4 + ks;
#pragma unroll
                for (int j = 0; j < 8; ++j) {
                    __bf16 hb = (__bf16)vv[j];
                    ah[r][j] = hb;
                    al[r][j] = (__bf16)(vv[j] - (float)hb);
                }
            }
    }
    float b1v[8], wsv[8];
#pragma unroll
    for (int ct = 0; ct < 8; ++ct) {
        b1v[ct] = b1[ct * 16 + n16];
        wsv[ct] = Ws[ct * 16 + n16];
    }
    const float bsv = bsp[0];

    // ---- zero AdjN ----
    for (int i = t; i < NPG * AS; i += NT) AdjN[i] = 0u;
    __syncthreads();

    // ---- phase: stage W1 -> LDS frag-pairs (hi-block|lo-block) + edge atomics ----
    // Fragment (ks,ct): lane holds B[k=ks*32+quad*8+j][n=ct*16+n16] as 8 bf16 (16B);
    // hi at pairbase + lane*16B, lo at pairbase + 1024B + lane*16B.
    {
#pragma unroll
        for (int i = 0; i < 4; ++i) {
            const int tau = i * NT + t;           // tile id, 1024 tiles of 4k x 4n
            const int ng = tau & 31, kg = tau >> 5;
            const int n0 = ng * 4, k0 = kg * 4;
            f4 r[4];
#pragma unroll
            for (int e = 0; e < 4; ++e)
                r[e] = *reinterpret_cast<const f4*>(W1 + (k0 + e) * HID + n0);
            const int p   = (k0 >> 5) * 8 + (n0 >> 4);
            const int j0h = (k0 & 7) >> 1;         // 0 or 2 (dword offset of j-block)
            const int l0  = ((k0 >> 3) & 3) * 16;
#pragma unroll
            for (int c = 0; c < 4; ++c) {
                const int lane0 = l0 + (n0 & 15) + c;
                unsigned hs[4], ls[4];
#pragma unroll
                for (int e = 0; e < 4; ++e) {
                    float v = r[e][c];
                    __bf16 hb = (__bf16)v;
                    __bf16 lb = (__bf16)(v - (float)hb);
                    hs[e] = bf2us(hb); ls[e] = bf2us(lb);
                }
                uint2 sh, sl;
                sh.x = hs[0] | (hs[1] << 16); sh.y = hs[2] | (hs[3] << 16);
                sl.x = ls[0] | (ls[1] << 16); sl.y = ls[2] | (ls[3] << 16);
                const int base = p * FS + lane0 * 4 + j0h;
                *reinterpret_cast<uint2*>(&HpT[base])       = sh;
                *reinterpret_cast<uint2*>(&HpT[base + 256]) = sl;
            }
        }
    }
#pragma unroll
    for (int i = 0; i < 8; ++i)
        atomicAdd(&AdjN[ed[i] * AS + (es[i] >> 3)], 1u << ((es[i] & 7) * 4));
    __syncthreads();   // W1 frags + adjacency complete (no diagonal yet)

    // ---- wave-parallel deg/rs for OWN 32 rows: 2 lanes/row sum 8 nibble-dwords
    //      each, shfl_xor(32) combine; redistribute to (quad,reg) via bpermute.
    //      Diagonal +1 deferred to the H0'-write phase (ordered by that barrier).
    f4 rs4[2];
    {
        const unsigned* row = &AdjN[(m0 + l2) * AS + half * 8];
        unsigned sum = 0;
#pragma unroll
        for (int w = 0; w < 8; ++w) {
            unsigned u = row[w];
            unsigned b = (u & 0x0F0F0F0Fu) + ((u >> 4) & 0x0F0F0F0Fu);
            sum += (b * 0x01010101u) >> 24;
        }
        sum += (unsigned)__shfl_xor((int)sum, 32, 64);
        float rs = rsqrtf((float)(sum + 1));
        if (lane < 32) rsl[m0 + lane] = rs;       // for the score phase later
        const int rvi = __float_as_int(rs);
#pragma unroll
        for (int rt = 0; rt < 2; ++rt)
#pragma unroll
            for (int reg = 0; reg < 4; ++reg)
                rs4[rt][reg] = __int_as_float(
                    __builtin_amdgcn_ds_bpermute(4 * (rt * 16 + quad * 4 + reg), rvi));
    }

    // ---- GEMM1 via MFMA, ct-pair-outer: H0 = (xh+xl)@(wh+wl), lo*lo dropped.
    //      Each pair's rs-scale + hi/lo pack runs in the next pairs' MFMA shadow;
    //      only the ds_writes wait for the barrier (phase A/B regions alias).
    uint2 shp[2][8], slp[2][8];
#pragma unroll
    for (int ctp = 0; ctp < 4; ++ctp) {
        f4 a2[2][2];
#pragma unroll
        for (int rt = 0; rt < 2; ++rt)
#pragma unroll
            for (int cc = 0; cc < 2; ++cc) {
                a2[rt][cc].x = 0.f; a2[rt][cc].y = 0.f;
                a2[rt][cc].z = 0.f; a2[rt][cc].w = 0.f;
            }
#pragma unroll
        for (int ks = 0; ks < 4; ++ks)
#pragma unroll
            for (int cc = 0; cc < 2; ++cc) {
                const int ct = ctp * 2 + cc;
                const unsigned* fp = &HpT[(ks * 8 + ct) * FS + lane * 4];
                bfrag bh = *reinterpret_cast<const bfrag*>(fp);
                bfrag bl = *reinterpret_cast<const bfrag*>(fp + 256);
#pragma unroll
                for (int rt = 0; rt < 2; ++rt) {
                    const int r = rt * 4 + ks;
                    a2[rt][cc] = __builtin_amdgcn_mfma_f32_16x16x32_bf16(ah[r], bh, a2[rt][cc], 0, 0, 0);
                    a2[rt][cc] = __builtin_amdgcn_mfma_f32_16x16x32_bf16(al[r], bh, a2[rt][cc], 0, 0, 0);
                    a2[rt][cc] = __builtin_amdgcn_mfma_f32_16x16x32_bf16(ah[r], bl, a2[rt][cc], 0, 0, 0);
                }
            }
#pragma unroll
        for (int rt = 0; rt < 2; ++rt)
#pragma unroll
            for (int cc = 0; cc < 2; ++cc) {
                const int ct = ctp * 2 + cc;
                unsigned hs[4], ls[4];
#pragma unroll
                for (int reg = 0; reg < 4; ++reg) {
                    float v = a2[rt][cc][reg] * rs4[rt][reg];
                    __bf16 hb = (__bf16)v;
                    __bf16 lb = (__bf16)(v - (float)hb);
                    hs[reg] = bf2us(hb); ls[reg] = bf2us(lb);
                }
                shp[rt][ct].x = hs[0] | (hs[1] << 16); shp[rt][ct].y = hs[2] | (hs[3] << 16);
                slp[rt][ct].x = ls[0] | (ls[1] << 16); slp[rt][ct].y = ls[2] | (ls[3] << 16);
            }
    }
    __syncthreads();   // all frag reads done -> HpT reusable for H0'

    // ---- H0' writes (pre-packed) + deferred adjacency diagonal ----
    {
        const int mbh = (m0 >> 1) + quad * 2;
#pragma unroll
        for (int rt = 0; rt < 2; ++rt)
#pragma unroll
            for (int ct = 0; ct < 8; ++ct) {
                const int rb = (ct * 16 + n16) * HS + mbh + rt * 8;
                *reinterpret_cast<uint2*>(&HpT[rb])      = shp[rt][ct];
                *reinterpret_cast<uint2*>(&HpT[rb + 64]) = slp[rt][ct];
            }
    }
    if (t < NPG)
        AdjN[t * AS + (t >> 3)] += 1u << ((t & 7) * 4);
    __syncthreads();

    // ---- conv1 aggregation via MFMA, ct-pair-outer: agg = (Adj+I) @ H0'(hi+lo);
    //      relu+bias epilogue and the h@Ws dot accumulate in the MFMA shadow ----
    bfrag af[4][2];
#pragma unroll
    for (int ks = 0; ks < 4; ++ks)
#pragma unroll
        for (int mt = 0; mt < 2; ++mt) {
            unsigned w = AdjN[(m0 + mt * 16 + n16) * AS + ks * 4 + quad];
#pragma unroll
            for (int j = 0; j < 8; ++j)
                af[ks][mt][j] = (__bf16)(float)((w >> (4 * j)) & 15u);
        }
    f4 hacc[2][8];
    float dot[2][4];
#pragma unroll
    for (int mt = 0; mt < 2; ++mt)
#pragma unroll
        for (int reg = 0; reg < 4; ++reg) dot[mt][reg] = 0.f;
#pragma unroll
    for (int ctp = 0; ctp < 4; ++ctp) {
#pragma unroll
        for (int mt = 0; mt < 2; ++mt)
#pragma unroll
            for (int cc = 0; cc < 2; ++cc) {
                const int ct = ctp * 2 + cc;
                hacc[mt][ct].x = 0.f; hacc[mt][ct].y = 0.f;
                hacc[mt][ct].z = 0.f; hacc[mt][ct].w = 0.f;
            }
#pragma unroll
        for (int ks = 0; ks < 4; ++ks)
#pragma unroll
            for (int cc = 0; cc < 2; ++cc) {
                const int ct = ctp * 2 + cc;
                const unsigned* bp = &HpT[(ct * 16 + n16) * HS + ks * 16 + quad * 4];
                bfrag bh = *reinterpret_cast<const bfrag*>(bp);
                bfrag bl = *reinterpret_cast<const bfrag*>(bp + 64);
#pragma unroll
                for (int mt = 0; mt < 2; ++mt) {
                    hacc[mt][ct] = __builtin_amdgcn_mfma_f32_16x16x32_bf16(af[ks][mt], bh, hacc[mt][ct], 0, 0, 0);
                    hacc[mt][ct] = __builtin_amdgcn_mfma_f32_16x16x32_bf16(af[ks][mt], bl, hacc[mt][ct], 0, 0, 0);
                }
            }
#pragma unroll
        for (int mt = 0; mt < 2; ++mt)
#pragma unroll
            for (int cc = 0; cc < 2; ++cc) {
                const int ct = ctp * 2 + cc;
#pragma unroll
                for (int reg = 0; reg < 4; ++reg) {
                    float v = fmaxf(hacc[mt][ct][reg] * rs4[mt][reg] + b1v[ct], 0.f);
                    hacc[mt][ct][reg] = v;
                    dot[mt][reg] += v * wsv[ct];
                }
            }
    }

    // ---- spl' = rs * (h @ Ws): shfl_xor reduce over n-group ----
    {
#pragma unroll
        for (int d = 1; d < 16; d <<= 1)
#pragma unroll
            for (int mt = 0; mt < 2; ++mt)
#pragma unroll
                for (int reg = 0; reg < 4; ++reg)
                    dot[mt][reg] += __shfl_xor(dot[mt][reg], d, 64);
        if (n16 == 0) {
#pragma unroll
            for (int mt = 0; mt < 2; ++mt)
#pragma unroll
                for (int reg = 0; reg < 4; ++reg)
                    spl[m0 + mt * 16 + quad * 4 + reg] = rs4[mt][reg] * dot[mt][reg];
        }
    }
    __syncthreads();   // spl ready; all agg frag reads done -> HpT reusable for Wlin

    // ---- score = rs * ((Adj+I) @ spl') + bs  (waves 0-1)
    // ---- overlapped: waves 2-3 stage Wlin -> HpT, 16-load batches ----
    if (t < NPG) {
        const unsigned* row = &AdjN[t * AS];
        float sc = 0.f;
#pragma unroll
        for (int w = 0; w < 16; ++w) {
            unsigned u = row[w];
            const float* sp = &spl[w * 8];
            sc += (float)(u & 15u)         * sp[0] + (float)((u >> 4)  & 15u) * sp[1]
                + (float)((u >> 8)  & 15u) * sp[2] + (float)((u >> 12) & 15u) * sp[3]
                + (float)((u >> 16) & 15u) * sp[4] + (float)((u >> 20) & 15u) * sp[5]
                + (float)((u >> 24) & 15u) * sp[6] + (float)(u >> 28)         * sp[7];
        }
        scl[t] = rsl[t] * sc + bsv;
    } else {
        const int tt = t - NPG;   // 0..127
        const f4* WL4 = reinterpret_cast<const f4*>(Wlin);
#pragma unroll
        for (int b2 = 0; b2 < 2; ++b2) {
            f4 w[16];
#pragma unroll
            for (int u = 0; u < 16; ++u)
                w[u] = WL4[(b2 * 16 + u) * 128 + tt];
#pragma unroll
            for (int u = 0; u < 16; ++u)
                *reinterpret_cast<f4*>(&HpT[((b2 * 16 + u) * 128 + tt) * 4]) = w[u];
        }
    }
    __syncthreads();

    // ---- top-K wave-redundant, barrier-free: 2 lanes/node compute half-range
    //      ranks, shfl_xor(32) combine; weights redistributed in-register ----
    float wm[2][4];
    {
        const int nd = m0 + l2;
        float v = scl[nd];
        int rank = 0;
#pragma unroll
        for (int j4 = 0; j4 < 16; ++j4) {
            const int jb = half * 64 + j4 * 4;
            float4 u = *reinterpret_cast<const float4*>(&scl[jb]);
            rank += (u.x > v || (u.x == v && jb     < nd)) ? 1 : 0;
            rank += (u.y > v || (u.y == v && jb + 1 < nd)) ? 1 : 0;
            rank += (u.z > v || (u.z == v && jb + 2 < nd)) ? 1 : 0;
            rank += (u.w > v || (u.w == v && jb + 3 < nd)) ? 1 : 0;
        }
        rank += __shfl_xor(rank, 32, 64);
        float wfull = (rank < KSEL) ? fast_tanh(v) * (1.0f / KSEL) : 0.f;
        const int wvi = __float_as_int(wfull);
#pragma unroll
        for (int mt = 0; mt < 2; ++mt)
#pragma unroll
            for (int reg = 0; reg < 4; ++reg)
                wm[mt][reg] = __int_as_float(
                    __builtin_amdgcn_ds_bpermute(4 * (mt * 16 + quad * 4 + reg), wvi));
    }

    // ---- pooled[c] = sum_m wgt[m]*h[m][c] from registers; shfl over quads ----
    {
        float p[8];
#pragma unroll
        for (int ct = 0; ct < 8; ++ct) {
            float s = 0.f;
#pragma unroll
            for (int mt = 0; mt < 2; ++mt)
#pragma unroll
                for (int reg = 0; reg < 4; ++reg)
                    s += wm[mt][reg] * hacc[mt][ct][reg];
            p[ct] = s;
        }
#pragma unroll
        for (int d = 16; d < 64; d <<= 1)
#pragma unroll
            for (int ct = 0; ct < 8; ++ct)
                p[ct] += __shfl_xor(p[ct], d, 64);
        if (quad == 0) {
#pragma unroll
            for (int ct = 0; ct < 8; ++ct)
                pp[wv * HID + ct * 16 + n16] = p[ct];
        }
    }
    __syncthreads();   // pp partials ready

    // ---- out = pooled @ Wlin + blin, Wlin in LDS; pooled summed from the 4
    //      per-wave partials on the fly (broadcast reads) ----
    {
        const int c4 = (t & 31) * 4, rg = t >> 5;   // rg in [0,8)
        f4 s4; s4.x = 0.f; s4.y = 0.f; s4.z = 0.f; s4.w = 0.f;
#pragma unroll 8
        for (int kk = 0; kk < 16; ++kk) {
            const int k = rg * 16 + kk;
            const float sk = pp[k] + pp[HID + k] + pp[2 * HID + k] + pp[3 * HID + k];
            const f4 w = *reinterpret_cast<const f4*>(&HpT[k * HID + c4]);
            s4.x += sk * w.x; s4.y += sk * w.y;
            s4.z += sk * w.z; s4.w += sk * w.w;
        }
        float* part = reinterpret_cast<float*>(AdjN);   // AdjN dead after score
        *reinterpret_cast<f4*>(&part[rg * HID + c4]) = s4;
    }
    __syncthreads();
    if (t < NPG) {
        const float* part = reinterpret_cast<const float*>(AdjN);
        float s = blin[t];
#pragma unroll
        for (int r = 0; r < 8; ++r) s += part[r * HID + t];
        out[(long)g * HID + t] = s;
    }
}

extern "C" void kernel_launch(void* const* d_in, const int* in_sizes, int n_in,
                              void* d_out, int out_size, void* d_ws, size_t ws_size,
                              hipStream_t stream) {
    const float* x    = (const float*)d_in[0];
    const int*   ei   = (const int*)  d_in[1];
    const float* W1   = (const float*)d_in[3];
    const float* b1   = (const float*)d_in[4];
    const float* Ws   = (const float*)d_in[5];
    const float* bs   = (const float*)d_in[6];
    const float* Wlin = (const float*)d_in[7];
    const float* blin = (const float*)d_in[8];
    float* out = (float*)d_out;

    const int E = in_sizes[1] / 2;          // 1048576
    const int nnodes = in_sizes[0] / HID;   // 65536
    const int B = nnodes / NPG;             // 512
    const int epg = E / B;                  // 2048

    sagpool_fused<<<B, NT, 0, stream>>>(x, ei, ei + E, W1, b1, Ws, bs,
                                        Wlin, blin, out, epg);
}